// Round 3
// baseline (102129.773 us; speedup 1.0000x reference)
//
#include <hip/hip_runtime.h>

// ---- problem dims ----
#define T_DIM 256
#define NCOL 4608   // 3 gates * NB * BS  (col index n = g*1536 + k*256 + h)
#define GRID_N 144  // persistent grid: 72 gi + 72 gh blocks; first 64 also run Phase B

typedef __bf16 bf16x8 __attribute__((ext_vector_type(8)));
typedef float f32x4 __attribute__((ext_vector_type(4)));

#define MFMA16(a, b, c) __builtin_amdgcn_mfma_f32_16x16x32_bf16((a), (b), (c), 0, 0, 0)

__device__ __forceinline__ unsigned short f2bf(float f) {
  unsigned u = __float_as_uint(f);
  unsigned r = u + 0x7FFFu + ((u >> 16) & 1u);
  return (unsigned short)(r >> 16);
}
__device__ __forceinline__ float bf2f(unsigned short s) {
  return __uint_as_float(((unsigned)s) << 16);
}
// split-bf16: x ~= hi + lo with |x - hi - lo| <= 2^-18 |x|
__device__ __forceinline__ void split2(float f, unsigned short* hi, unsigned short* lo) {
  unsigned short h = f2bf(f);
  *hi = h;
  *lo = f2bf(f - bf2f(h));
}

__device__ __forceinline__ void pack8_split(const float* p, bf16x8* hi, bf16x8* lo) {
  union { unsigned short s[8]; bf16x8 v; } uh, ul;
#pragma unroll
  for (int i = 0; i < 8; ++i) split2(p[i], &uh.s[i], &ul.s[i]);
  *hi = uh.v;
  *lo = ul.v;
}

__device__ __forceinline__ float sigm(float x) { return 1.f / (1.f + expf(-x)); }

// ================= precompute kernels =================

// weight transposes to split-bf16 hi/lo planes (K-contiguous rows for MFMA B-frags)
__global__ void convert_weights(const float* __restrict__ wv, const float* __restrict__ wi,
                                const float* __restrict__ wh,
                                unsigned short* __restrict__ wv_hi, unsigned short* __restrict__ wv_lo,
                                unsigned short* __restrict__ wi_hi, unsigned short* __restrict__ wi_lo,
                                unsigned short* __restrict__ wh_hi, unsigned short* __restrict__ wh_lo) {
  const size_t N0 = 1024u * 1536u;
  const size_t N1 = 18u * 256u * 1024u;
  const size_t N2 = 18u * 256u * 256u;
  for (size_t idx = blockIdx.x * 256u + threadIdx.x; idx < N0 + N1 + N2;
       idx += (size_t)gridDim.x * 256u) {
    if (idx < N0) {
      size_t n = idx / 1536u, kk = idx % 1536u;
      split2(wv[kk * 1024u + n], &wv_hi[idx], &wv_lo[idx]);
    } else if (idx < N0 + N1) {
      size_t r = idx - N0;
      size_t gk = r / 262144u, rem = r % 262144u;
      size_t h = rem / 1024u, kk = rem % 1024u;
      split2(wi[gk * 262144u + kk * 256u + h], &wi_hi[r], &wi_lo[r]);
    } else {
      size_t r = idx - N0 - N1;
      size_t gk = r / 65536u, rem = r % 65536u;
      size_t nout = rem / 256u, kin = rem % 256u;
      split2(wh[gk * 65536u + kin * 256u + nout], &wh_hi[r], &wh_lo[r]);
    }
  }
}

// kx[t*64+b][64] = x @ wk + bk  -- exact fp32 (feeds discrete top-k decisions)
__global__ void kx_kernel(const float* __restrict__ x, const float* __restrict__ wk,
                          const float* __restrict__ bk, float* __restrict__ kx) {
  __shared__ float xs[16][64];
  const int mb = blockIdx.x;
  const int tid = threadIdx.x;
  const int mi = tid >> 6, n = tid & 63;
  float acc[4] = {0.f, 0.f, 0.f, 0.f};
  for (int kk0 = 0; kk0 < 1536; kk0 += 64) {
    __syncthreads();
    for (int i = tid; i < 1024; i += 256) {
      int r = i >> 6, c = i & 63;
      xs[r][c] = x[(size_t)(mb * 16 + r) * 1536u + kk0 + c];
    }
    __syncthreads();
    for (int c = 0; c < 64; ++c) {
      float w = wk[(size_t)(kk0 + c) * 64u + n];
      acc[0] += xs[mi][c] * w;
      acc[1] += xs[mi + 4][c] * w;
      acc[2] += xs[mi + 8][c] * w;
      acc[3] += xs[mi + 12][c] * w;
    }
  }
  for (int i = 0; i < 4; ++i)
    kx[(size_t)(mb * 16 + mi + 4 * i) * 64u + n] = acc[i] + bk[n];
}

// xv = x @ wv + bv via split-bf16 MFMA (3-term), output stored as hi/lo planes
__global__ __launch_bounds__(256) void xv_gemm(const float* __restrict__ x,
                                               const unsigned short* __restrict__ wv_hi,
                                               const unsigned short* __restrict__ wv_lo,
                                               const float* __restrict__ bv,
                                               unsigned short* __restrict__ xv_hi,
                                               unsigned short* __restrict__ xv_lo) {
  const int nb = blockIdx.x, mb = blockIdx.y;  // 8 x 128
  const int tid = threadIdx.x;
  const int w = tid >> 6, lane = tid & 63;
  const int mh = w >> 1, nh = w & 1;
  const int row = lane & 15, q8 = (lane >> 4) * 8;
  const int m0 = mb * 128 + mh * 64;
  const int n0 = nb * 128 + nh * 64;
  f32x4 acc[4][4];
#pragma unroll
  for (int i = 0; i < 4; ++i)
#pragma unroll
    for (int j = 0; j < 4; ++j) acc[i][j] = (f32x4){0.f, 0.f, 0.f, 0.f};
  for (int kk = 0; kk < 1536; kk += 32) {
    bf16x8 ah[4], al[4], bh[4], bl[4];
#pragma unroll
    for (int mt = 0; mt < 4; ++mt)
      pack8_split(x + (size_t)(m0 + mt * 16 + row) * 1536u + kk + q8, &ah[mt], &al[mt]);
#pragma unroll
    for (int nt = 0; nt < 4; ++nt) {
      size_t off = (size_t)(n0 + nt * 16 + row) * 1536u + kk + q8;
      bh[nt] = *(const bf16x8*)(wv_hi + off);
      bl[nt] = *(const bf16x8*)(wv_lo + off);
    }
#pragma unroll
    for (int mt = 0; mt < 4; ++mt)
#pragma unroll
      for (int nt = 0; nt < 4; ++nt) {
        acc[mt][nt] = MFMA16(ah[mt], bh[nt], acc[mt][nt]);
        acc[mt][nt] = MFMA16(al[mt], bh[nt], acc[mt][nt]);
        acc[mt][nt] = MFMA16(ah[mt], bl[nt], acc[mt][nt]);
      }
  }
  const int quad = lane >> 4, col = lane & 15;
#pragma unroll
  for (int mt = 0; mt < 4; ++mt)
#pragma unroll
    for (int nt = 0; nt < 4; ++nt)
#pragma unroll
      for (int r = 0; r < 4; ++r) {
        int m = m0 + mt * 16 + quad * 4 + r;
        int n = n0 + nt * 16 + col;
        split2(acc[mt][nt][r] + bv[n], &xv_hi[(size_t)m * 1024u + n],
               &xv_lo[(size_t)m * 1024u + n]);
      }
}

// c0[gk][h] = bv @ wi[gk]   (null-slot value path; exact fp32)
__global__ void c0_kernel(const float* __restrict__ bv, const float* __restrict__ wi,
                          float* __restrict__ c0) {
  const int gk = blockIdx.x, h = threadIdx.x;
  const float* wp = wi + (size_t)gk * 262144u + h;
  float acc = 0.f;
  for (int kk = 0; kk < 1024; ++kk) acc += bv[kk] * wp[(size_t)kk * 256u];
  c0[gk * 256 + h] = acc;
}

// ================= persistent kernel =================

struct KParams {
  const float *h_in, *wq, *bq, *bk;
  const float *bi, *bh;
  const float *cq, *cbq, *ck, *cbk, *cv, *cbv, *cfc, *cbfc, *ln_g, *ln_b;
  const unsigned short *xv_hi, *xv_lo, *wi_hi, *wi_lo, *wh_hi, *wh_lo;
  const float *kx, *c0;
  float *gi_raw, *gh_raw;
  unsigned short *h_hi, *h_lo;
  unsigned* bar;
  float* out;
};

// grid barrier with explicit agent-scope fences (buffer_wbl2 / buffer_inv):
// __syncthreads drains block stores; tid0's release fence writes back this
// XCD's L2; acquire fence after the spin invalidates L1+L2 -> fresh reads.
__device__ __forceinline__ void gbar(unsigned* bar, unsigned target) {
  __syncthreads();
  if (threadIdx.x == 0) {
    __threadfence();
    __hip_atomic_fetch_add(bar, 1u, __ATOMIC_RELAXED, __HIP_MEMORY_SCOPE_AGENT);
    while (__hip_atomic_load(bar, __ATOMIC_RELAXED, __HIP_MEMORY_SCOPE_AGENT) < target) {
      __builtin_amdgcn_s_sleep(2);
    }
    __threadfence();
  }
  __syncthreads();
}

__device__ __forceinline__ void block_sum2(float a, float c, float* redA, float* redC,
                                           int tid, float* outA, float* outC) {
  for (int off = 32; off; off >>= 1) {
    a += __shfl_down(a, off);
    c += __shfl_down(c, off);
  }
  if ((tid & 63) == 0) {
    redA[tid >> 6] = a;
    redC[tid >> 6] = c;
  }
  __syncthreads();
  *outA = redA[0] + redA[1] + redA[2] + redA[3];
  *outC = redC[0] + redC[1] + redC[2] + redC[3];
  __syncthreads();
}

// input-attention softmax for step tstep, batch b (fp32 end-to-end)
__device__ __forceinline__ void compute_att(const KParams& p, int b, int tstep, int tid,
                                            float (*hs)[256], float (*qv)[64],
                                            float* att0l, float* att1l) {
  for (int jj = tid; jj < 384; jj += 256) {
    int kb = jj >> 6, c = jj & 63;
    float acc = p.bq[c];
    for (int j = 0; j < 256; ++j) acc += hs[kb][j] * p.wq[j * 64 + c];
    qv[kb][c] = acc;
  }
  __syncthreads();
  if (tid < 64) {
    const float* kxr = p.kx + ((size_t)tstep * 64u + b) * 64u;
    float bkv = p.bk[tid], kxv = kxr[tid];
    for (int kb = 0; kb < 6; ++kb) {
      float q = qv[kb][tid];
      float p0 = q * bkv, p1 = q * kxv;
      for (int off = 32; off; off >>= 1) {
        p0 += __shfl_down(p0, off);
        p1 += __shfl_down(p1, off);
      }
      if (tid == 0) {
        float s0 = p0 * 0.125f, s1 = p1 * 0.125f;  // temperature sqrt(64)=8
        float mx = fmaxf(s0, s1);
        float e0 = expf(s0 - mx), e1 = expf(s1 - mx);
        float inv = 1.f / (e0 + e1);
        att0l[kb] = e0 * inv;
        att1l[kb] = e1 * inv;
      }
    }
  }
  __syncthreads();
}

__global__ __launch_bounds__(256) void rims_seq(KParams p) {
  const int bid = blockIdx.x, tid = threadIdx.x;
  const int wv_ = tid >> 6, lane = tid & 63;
  const int b = bid;  // Phase B identity (bid < 64)

  __shared__ float hs[6][256];
  __shared__ float hx[6][256];
  __shared__ float q2s[6][64], k2s[6][64], v2s[6][64], o2s[6][64];
  __shared__ float qv[6][64];
  __shared__ float scl[4][6][6], a2l[4][6][6];
  __shared__ float att0l[6], att1l[6], maskl[6];
  __shared__ float redA[4], redC[4];

  unsigned nbar = 0;

  // ---- init: load h0, publish split-bf16 copy, att(0) ----
  if (bid < 64) {
    for (int kp = 0; kp < 6; ++kp) {
      float h0 = p.h_in[(size_t)b * 1536u + kp * 256 + tid];
      hs[kp][tid] = h0;
      split2(h0, &p.h_hi[(size_t)b * 1536u + kp * 256 + tid],
             &p.h_lo[(size_t)b * 1536u + kp * 256 + tid]);
    }
    __syncthreads();
    compute_att(p, b, 0, tid, hs, qv, att0l, att1l);
  }
  ++nbar; gbar(p.bar, nbar * GRID_N);

  for (int t = 0; t < T_DIM; ++t) {
    // ======== Phase A: gi_raw = xv[t] @ wi ; gh_raw = h @ wh (split-bf16 MFMA) ========
    if (bid < 72) {
      const int n0 = bid * 64;
      const int row = lane & 15, q8 = (lane >> 4) * 8;
      const size_t aoff = ((size_t)t * 64u + wv_ * 16 + row) * 1024u + q8;
      f32x4 acc[4];
#pragma unroll
      for (int nt = 0; nt < 4; ++nt) acc[nt] = (f32x4){0.f, 0.f, 0.f, 0.f};
      for (int kk = 0; kk < 1024; kk += 32) {
        bf16x8 ah = *(const bf16x8*)(p.xv_hi + aoff + kk);
        bf16x8 al = *(const bf16x8*)(p.xv_lo + aoff + kk);
#pragma unroll
        for (int nt = 0; nt < 4; ++nt) {
          size_t boff = (size_t)(n0 + nt * 16 + row) * 1024u + kk + q8;
          bf16x8 bh = *(const bf16x8*)(p.wi_hi + boff);
          bf16x8 bl = *(const bf16x8*)(p.wi_lo + boff);
          acc[nt] = MFMA16(ah, bh, acc[nt]);
          acc[nt] = MFMA16(al, bh, acc[nt]);
          acc[nt] = MFMA16(ah, bl, acc[nt]);
        }
      }
      const int quad = lane >> 4, col = lane & 15;
#pragma unroll
      for (int nt = 0; nt < 4; ++nt)
#pragma unroll
        for (int r = 0; r < 4; ++r) {
          int m = wv_ * 16 + quad * 4 + r;
          p.gi_raw[(size_t)m * NCOL + n0 + nt * 16 + col] = acc[nt][r];
        }
    } else {
      const int j = bid - 72;
      const int gk = j >> 2, q4 = j & 3;
      const int kbb = gk % 6;
      const int nloc0 = q4 * 64;
      const int n0 = (gk / 6) * 1536 + kbb * 256 + nloc0;
      const int row = lane & 15, q8 = (lane >> 4) * 8;
      const size_t aoff = (size_t)(wv_ * 16 + row) * 1536u + kbb * 256 + q8;
      const size_t bbase = (size_t)gk * 65536u;
      f32x4 acc[4];
#pragma unroll
      for (int nt = 0; nt < 4; ++nt) acc[nt] = (f32x4){0.f, 0.f, 0.f, 0.f};
      for (int kk = 0; kk < 256; kk += 32) {
        bf16x8 ah = *(const bf16x8*)(p.h_hi + aoff + kk);
        bf16x8 al = *(const bf16x8*)(p.h_lo + aoff + kk);
#pragma unroll
        for (int nt = 0; nt < 4; ++nt) {
          size_t boff = bbase + (size_t)(nloc0 + nt * 16 + row) * 256u + q8 + kk;
          bf16x8 bh = *(const bf16x8*)(p.wh_hi + boff);
          bf16x8 bl = *(const bf16x8*)(p.wh_lo + boff);
          acc[nt] = MFMA16(ah, bh, acc[nt]);
          acc[nt] = MFMA16(al, bh, acc[nt]);
          acc[nt] = MFMA16(ah, bl, acc[nt]);
        }
      }
      const int quad = lane >> 4, col = lane & 15;
#pragma unroll
      for (int nt = 0; nt < 4; ++nt)
#pragma unroll
        for (int r = 0; r < 4; ++r) {
          int m = wv_ * 16 + quad * 4 + r;
          p.gh_raw[(size_t)m * NCOL + n0 + nt * 16 + col] = acc[nt][r];
        }
    }
    ++nbar; gbar(p.bar, nbar * GRID_N);

    // ======== Phase B: one block per b ========
    if (bid < 64) {
      if (tid < 6) {
        float my = att0l[tid];
        int cnt = 0;
        for (int k2 = 0; k2 < 6; ++k2)
          if (att0l[k2] > my || (att0l[k2] == my && k2 < tid)) cnt++;
        maskl[tid] = (cnt < 2) ? 0.f : 1.f;  // 2 largest-null blocks inactive
      }
      __syncthreads();

      // GRU (gate order r,z,n)
      for (int kp = 0; kp < 6; ++kp) {
        float a1 = att1l[kp], a0 = att0l[kp];
        size_t base = (size_t)b * NCOL + kp * 256 + tid;
        int ci = kp * 256 + tid;
        float gi0 = a1 * p.gi_raw[base] + a0 * p.c0[ci] + p.bi[ci];
        float gi1 = a1 * p.gi_raw[base + 1536] + a0 * p.c0[1536 + ci] + p.bi[1536 + ci];
        float gi2 = a1 * p.gi_raw[base + 3072] + a0 * p.c0[3072 + ci] + p.bi[3072 + ci];
        float gh0 = p.gh_raw[base] + p.bh[ci];
        float gh1 = p.gh_raw[base + 1536] + p.bh[1536 + ci];
        float gh2 = p.gh_raw[base + 3072] + p.bh[3072 + ci];
        float r = sigm(gi0 + gh0);
        float z = sigm(gi1 + gh1);
        float n = tanhf(gi2 + r * gh2);
        hx[kp][tid] = (1.f - z) * n + z * hs[kp][tid];
      }
      __syncthreads();

      // q2/k2/v2 for all 6 blocks: 1152 dot-256 jobs
      for (int jj = tid; jj < 1152; jj += 256) {
        int type = jj / 384;
        int r = jj - type * 384;
        int kp = r >> 6, c = r & 63;
        const float* W = (type == 0) ? p.cq : (type == 1) ? p.ck : p.cv;
        float acc = ((type == 0) ? p.cbq : (type == 1) ? p.cbk : p.cbv)[c];
        for (int j = 0; j < 256; ++j) acc += hx[kp][j] * W[j * 64 + c];
        float* dst = (type == 0) ? &q2s[kp][c] : (type == 1) ? &k2s[kp][c] : &v2s[kp][c];
        *dst = acc;
      }
      __syncthreads();

      // scores (temperature sqrt(16)=4)
      if (tid < 144) {
        int hh = tid / 36, rem = tid % 36, qq = rem / 6, kk2 = rem % 6;
        float acc = 0.f;
        for (int d = 0; d < 16; ++d) acc += q2s[qq][hh * 16 + d] * k2s[kk2][hh * 16 + d];
        scl[hh][qq][kk2] = acc * 0.25f;
      }
      __syncthreads();
      if (tid < 24) {
        int hh = tid / 6, qq = tid % 6;
        float mx = -1e30f;
        for (int k2 = 0; k2 < 6; ++k2) mx = fmaxf(mx, scl[hh][qq][k2]);
        float s = 0.f;
        for (int k2 = 0; k2 < 6; ++k2) {
          float e = expf(scl[hh][qq][k2] - mx);
          a2l[hh][qq][k2] = e;
          s += e;
        }
        float inv = 1.f / s;
        for (int k2 = 0; k2 < 6; ++k2) a2l[hh][qq][k2] *= inv;
      }
      __syncthreads();
      for (int jj = tid; jj < 384; jj += 256) {
        int qq = jj >> 6, c = jj & 63, hh = c >> 4;
        float acc = 0.f;
        for (int k2 = 0; k2 < 6; ++k2) acc += a2l[hh][qq][k2] * v2s[k2][c];
        o2s[qq][c] = acc;
      }
      __syncthreads();

      // res = o2 @ cfc + cbfc + hx
      float rr[6];
      for (int kp = 0; kp < 6; ++kp) {
        float acc = p.cbfc[tid] + hx[kp][tid];
        for (int c = 0; c < 64; ++c) acc += o2s[kp][c] * p.cfc[c * 256 + tid];
        rr[kp] = acc;
      }
      __syncthreads();

      // LayerNorm + gated update
      for (int kp = 0; kp < 6; ++kp) {
        float s, sq;
        block_sum2(rr[kp], rr[kp] * rr[kp], redA, redC, tid, &s, &sq);
        float mu = s * (1.f / 256.f);
        float var = sq * (1.f / 256.f) - mu * mu;
        float normed = (rr[kp] - mu) / sqrtf(var + 1e-5f);
        float hxf = hx[kp][tid] + normed * p.ln_g[tid] + p.ln_b[tid];
        float m = maskl[kp];
        float hn = m * hxf + (1.f - m) * hs[kp][tid];
        hs[kp][tid] = hn;
        size_t oidx = ((size_t)t * 64u + b) * 1536u + kp * 256 + tid;
        p.out[oidx] = hn;
        if (t == T_DIM - 1) p.out[25165824u + (size_t)b * 1536u + kp * 256 + tid] = hn;
        split2(hn, &p.h_hi[(size_t)b * 1536u + kp * 256 + tid],
               &p.h_lo[(size_t)b * 1536u + kp * 256 + tid]);
      }
      __syncthreads();

      if (t < T_DIM - 1) compute_att(p, b, t + 1, tid, hs, qv, att0l, att1l);
    }
    ++nbar; gbar(p.bar, nbar * GRID_N);
  }
}

// ================= host =================

extern "C" void kernel_launch(void* const* d_in, const int* in_sizes, int n_in, void* d_out,
                              int out_size, void* d_ws, size_t ws_size, hipStream_t stream) {
  (void)in_sizes; (void)n_in; (void)out_size; (void)ws_size;
  const float* inp = (const float*)d_in[0];
  const float* h_in = (const float*)d_in[1];
  const float* wq = (const float*)d_in[2];
  const float* bq = (const float*)d_in[3];
  const float* wk = (const float*)d_in[4];
  const float* bk = (const float*)d_in[5];
  const float* wv = (const float*)d_in[6];
  const float* bv = (const float*)d_in[7];
  const float* wi = (const float*)d_in[8];
  const float* wh = (const float*)d_in[9];
  const float* bi = (const float*)d_in[10];
  const float* bh = (const float*)d_in[11];
  const float* cq = (const float*)d_in[12];
  const float* cbq = (const float*)d_in[13];
  const float* ck = (const float*)d_in[14];
  const float* cbk = (const float*)d_in[15];
  const float* cv = (const float*)d_in[16];
  const float* cbv = (const float*)d_in[17];
  const float* cfc = (const float*)d_in[18];
  const float* cbfc = (const float*)d_in[19];
  const float* ln_g = (const float*)d_in[20];
  const float* ln_b = (const float*)d_in[21];

  char* ws = (char*)d_ws;
  const size_t o_wv_hi = 0;           // 3,145,728
  const size_t o_wv_lo = 3145728;     // 3,145,728
  const size_t o_wi_hi = 6291456;     // 9,437,184
  const size_t o_wi_lo = 15728640;    // 9,437,184
  const size_t o_wh_hi = 25165824;    // 2,359,296
  const size_t o_wh_lo = 27525120;    // 2,359,296
  const size_t o_xv_hi = 29884416;    // 33,554,432
  const size_t o_xv_lo = 63438848;    // 33,554,432
  const size_t o_kx = 96993280;       // 4,194,304
  const size_t o_c0 = 101187584;      // 18,432
  const size_t o_gi = 101206016;      // 1,179,648
  const size_t o_gh = 102385664;      // 1,179,648
  const size_t o_hhi = 103565312;     // 196,608
  const size_t o_hlo = 103761920;     // 196,608
  const size_t o_bar = 103958528;     // 256  (total ~99.1 MiB)

  unsigned short* wv_hi = (unsigned short*)(ws + o_wv_hi);
  unsigned short* wv_lo = (unsigned short*)(ws + o_wv_lo);
  unsigned short* wi_hi = (unsigned short*)(ws + o_wi_hi);
  unsigned short* wi_lo = (unsigned short*)(ws + o_wi_lo);
  unsigned short* wh_hi = (unsigned short*)(ws + o_wh_hi);
  unsigned short* wh_lo = (unsigned short*)(ws + o_wh_lo);
  unsigned short* xv_hi = (unsigned short*)(ws + o_xv_hi);
  unsigned short* xv_lo = (unsigned short*)(ws + o_xv_lo);
  float* kx = (float*)(ws + o_kx);
  float* c0 = (float*)(ws + o_c0);

  hipMemsetAsync(ws + o_bar, 0, 256, stream);
  convert_weights<<<2048, 256, 0, stream>>>(wv, wi, wh, wv_hi, wv_lo, wi_hi, wi_lo, wh_hi, wh_lo);
  kx_kernel<<<1024, 256, 0, stream>>>(inp, wk, bk, kx);
  xv_gemm<<<dim3(8, 128), 256, 0, stream>>>(inp, wv_hi, wv_lo, bv, xv_hi, xv_lo);
  c0_kernel<<<18, 256, 0, stream>>>(bv, wi, c0);

  KParams prm;
  prm.h_in = h_in; prm.wq = wq; prm.bq = bq; prm.bk = bk;
  prm.bi = bi; prm.bh = bh;
  prm.cq = cq; prm.cbq = cbq; prm.ck = ck; prm.cbk = cbk;
  prm.cv = cv; prm.cbv = cbv; prm.cfc = cfc; prm.cbfc = cbfc;
  prm.ln_g = ln_g; prm.ln_b = ln_b;
  prm.xv_hi = xv_hi; prm.xv_lo = xv_lo;
  prm.wi_hi = wi_hi; prm.wi_lo = wi_lo;
  prm.wh_hi = wh_hi; prm.wh_lo = wh_lo;
  prm.kx = kx; prm.c0 = c0;
  prm.gi_raw = (float*)(ws + o_gi);
  prm.gh_raw = (float*)(ws + o_gh);
  prm.h_hi = (unsigned short*)(ws + o_hhi);
  prm.h_lo = (unsigned short*)(ws + o_hlo);
  prm.bar = (unsigned*)(ws + o_bar);
  prm.out = (float*)d_out;

  rims_seq<<<GRID_N, 256, 0, stream>>>(prm);
}

// Round 4
// 99788.727 us; speedup vs baseline: 1.0235x; 1.0235x over previous
//
#include <hip/hip_runtime.h>

// ---- problem dims ----
#define T_DIM 256
#define NCOL 4608   // 3 gates * NB * BS  (col index n = g*1536 + k*256 + h)
#define GRID_N 144  // persistent grid: 72 gi + 72 gh blocks; first 64 also run Phase B

typedef __bf16 bf16x8 __attribute__((ext_vector_type(8)));
typedef float f32x4 __attribute__((ext_vector_type(4)));

#define MFMA16(a, b, c) __builtin_amdgcn_mfma_f32_16x16x32_bf16((a), (b), (c), 0, 0, 0)

#define CLOAD_F(ptr) __hip_atomic_load((ptr), __ATOMIC_RELAXED, __HIP_MEMORY_SCOPE_AGENT)
#define CSTORE_F(ptr, v) __hip_atomic_store((ptr), (v), __ATOMIC_RELAXED, __HIP_MEMORY_SCOPE_AGENT)

__device__ __forceinline__ unsigned short f2bf(float f) {
  unsigned u = __float_as_uint(f);
  unsigned r = u + 0x7FFFu + ((u >> 16) & 1u);
  return (unsigned short)(r >> 16);
}
__device__ __forceinline__ float bf2f(unsigned short s) {
  return __uint_as_float(((unsigned)s) << 16);
}
// split-bf16: x ~= hi + lo with |x - hi - lo| <= 2^-18 |x|
__device__ __forceinline__ void split2(float f, unsigned short* hi, unsigned short* lo) {
  unsigned short h = f2bf(f);
  *hi = h;
  *lo = f2bf(f - bf2f(h));
}

__device__ __forceinline__ void pack8_split(const float* p, bf16x8* hi, bf16x8* lo) {
  union { unsigned short s[8]; bf16x8 v; } uh, ul;
#pragma unroll
  for (int i = 0; i < 8; ++i) split2(p[i], &uh.s[i], &ul.s[i]);
  *hi = uh.v;
  *lo = ul.v;
}

__device__ __forceinline__ float sigm(float x) { return 1.f / (1.f + expf(-x)); }

// ================= precompute kernels =================

// weight transposes to split-bf16 hi/lo planes (K-contiguous rows for MFMA B-frags)
__global__ void convert_weights(const float* __restrict__ wv, const float* __restrict__ wi,
                                const float* __restrict__ wh,
                                unsigned short* __restrict__ wv_hi, unsigned short* __restrict__ wv_lo,
                                unsigned short* __restrict__ wi_hi, unsigned short* __restrict__ wi_lo,
                                unsigned short* __restrict__ wh_hi, unsigned short* __restrict__ wh_lo) {
  const size_t N0 = 1024u * 1536u;
  const size_t N1 = 18u * 256u * 1024u;
  const size_t N2 = 18u * 256u * 256u;
  for (size_t idx = blockIdx.x * 256u + threadIdx.x; idx < N0 + N1 + N2;
       idx += (size_t)gridDim.x * 256u) {
    if (idx < N0) {
      size_t n = idx / 1536u, kk = idx % 1536u;
      split2(wv[kk * 1024u + n], &wv_hi[idx], &wv_lo[idx]);
    } else if (idx < N0 + N1) {
      size_t r = idx - N0;
      size_t gk = r / 262144u, rem = r % 262144u;
      size_t h = rem / 1024u, kk = rem % 1024u;
      split2(wi[gk * 262144u + kk * 256u + h], &wi_hi[r], &wi_lo[r]);
    } else {
      size_t r = idx - N0 - N1;
      size_t gk = r / 65536u, rem = r % 65536u;
      size_t nout = rem / 256u, kin = rem % 256u;
      split2(wh[gk * 65536u + kin * 256u + nout], &wh_hi[r], &wh_lo[r]);
    }
  }
}

// kx[t*64+b][64] = x @ wk + bk  -- exact fp32 (feeds discrete top-k decisions)
__global__ void kx_kernel(const float* __restrict__ x, const float* __restrict__ wk,
                          const float* __restrict__ bk, float* __restrict__ kx) {
  __shared__ float xs[16][64];
  const int mb = blockIdx.x;
  const int tid = threadIdx.x;
  const int mi = tid >> 6, n = tid & 63;
  float acc[4] = {0.f, 0.f, 0.f, 0.f};
  for (int kk0 = 0; kk0 < 1536; kk0 += 64) {
    __syncthreads();
    for (int i = tid; i < 1024; i += 256) {
      int r = i >> 6, c = i & 63;
      xs[r][c] = x[(size_t)(mb * 16 + r) * 1536u + kk0 + c];
    }
    __syncthreads();
    for (int c = 0; c < 64; ++c) {
      float w = wk[(size_t)(kk0 + c) * 64u + n];
      acc[0] += xs[mi][c] * w;
      acc[1] += xs[mi + 4][c] * w;
      acc[2] += xs[mi + 8][c] * w;
      acc[3] += xs[mi + 12][c] * w;
    }
  }
  for (int i = 0; i < 4; ++i)
    kx[(size_t)(mb * 16 + mi + 4 * i) * 64u + n] = acc[i] + bk[n];
}

// xv = x @ wv + bv via split-bf16 MFMA (3-term), output stored as hi/lo planes
__global__ __launch_bounds__(256) void xv_gemm(const float* __restrict__ x,
                                               const unsigned short* __restrict__ wv_hi,
                                               const unsigned short* __restrict__ wv_lo,
                                               const float* __restrict__ bv,
                                               unsigned short* __restrict__ xv_hi,
                                               unsigned short* __restrict__ xv_lo) {
  const int nb = blockIdx.x, mb = blockIdx.y;  // 8 x 128
  const int tid = threadIdx.x;
  const int w = tid >> 6, lane = tid & 63;
  const int mh = w >> 1, nh = w & 1;
  const int row = lane & 15, q8 = (lane >> 4) * 8;
  const int m0 = mb * 128 + mh * 64;
  const int n0 = nb * 128 + nh * 64;
  f32x4 acc[4][4];
#pragma unroll
  for (int i = 0; i < 4; ++i)
#pragma unroll
    for (int j = 0; j < 4; ++j) acc[i][j] = (f32x4){0.f, 0.f, 0.f, 0.f};
  for (int kk = 0; kk < 1536; kk += 32) {
    bf16x8 ah[4], al[4], bh[4], bl[4];
#pragma unroll
    for (int mt = 0; mt < 4; ++mt)
      pack8_split(x + (size_t)(m0 + mt * 16 + row) * 1536u + kk + q8, &ah[mt], &al[mt]);
#pragma unroll
    for (int nt = 0; nt < 4; ++nt) {
      size_t off = (size_t)(n0 + nt * 16 + row) * 1536u + kk + q8;
      bh[nt] = *(const bf16x8*)(wv_hi + off);
      bl[nt] = *(const bf16x8*)(wv_lo + off);
    }
#pragma unroll
    for (int mt = 0; mt < 4; ++mt)
#pragma unroll
      for (int nt = 0; nt < 4; ++nt) {
        acc[mt][nt] = MFMA16(ah[mt], bh[nt], acc[mt][nt]);
        acc[mt][nt] = MFMA16(al[mt], bh[nt], acc[mt][nt]);
        acc[mt][nt] = MFMA16(ah[mt], bl[nt], acc[mt][nt]);
      }
  }
  const int quad = lane >> 4, col = lane & 15;
#pragma unroll
  for (int mt = 0; mt < 4; ++mt)
#pragma unroll
    for (int nt = 0; nt < 4; ++nt)
#pragma unroll
      for (int r = 0; r < 4; ++r) {
        int m = m0 + mt * 16 + quad * 4 + r;
        int n = n0 + nt * 16 + col;
        split2(acc[mt][nt][r] + bv[n], &xv_hi[(size_t)m * 1024u + n],
               &xv_lo[(size_t)m * 1024u + n]);
      }
}

// c0[gk][h] = bv @ wi[gk]   (null-slot value path; exact fp32)
__global__ void c0_kernel(const float* __restrict__ bv, const float* __restrict__ wi,
                          float* __restrict__ c0) {
  const int gk = blockIdx.x, h = threadIdx.x;
  const float* wp = wi + (size_t)gk * 262144u + h;
  float acc = 0.f;
  for (int kk = 0; kk < 1024; ++kk) acc += bv[kk] * wp[(size_t)kk * 256u];
  c0[gk * 256 + h] = acc;
}

// ================= persistent kernel =================

struct KParams {
  const float *h_in, *wq, *bq, *bk;
  const float *bi, *bh;
  const float *cq, *cbq, *ck, *cbk, *cv, *cbv, *cfc, *cbfc, *ln_g, *ln_b;
  const unsigned short *xv_hi, *xv_lo, *wi_hi, *wi_lo, *wh_hi, *wh_lo;
  const float *kx, *c0;
  float *gi_raw, *gh_raw;     // device-coherent (AGENT-scope accesses only)
  unsigned* h_pack;           // (hi<<16)|lo packed split-bf16 h; device-coherent
  unsigned* bar;              // 8 split counters, 128 B apart
  float* out;
};

// Grid barrier WITHOUT L2 flush: cross-block data moves via sc0/sc1 coherent
// accesses (never cached in stale L2), so the barrier only needs the counter.
// 8 split counter lines cut same-line RMW serialization 144 -> 18.
__device__ __forceinline__ void gbar(unsigned* bar, unsigned nbar) {
  __syncthreads();  // drains vmcnt: all coherent stores have reached the coherence point
  if (threadIdx.x == 0) {
    __hip_atomic_fetch_add(&bar[(blockIdx.x & 7) * 32], 1u, __ATOMIC_RELAXED,
                           __HIP_MEMORY_SCOPE_AGENT);
    const unsigned target = nbar * GRID_N;
    for (;;) {
      unsigned s = 0;
#pragma unroll
      for (int i = 0; i < 8; ++i)
        s += __hip_atomic_load(&bar[i * 32], __ATOMIC_RELAXED, __HIP_MEMORY_SCOPE_AGENT);
      if (s >= target) break;
      __builtin_amdgcn_s_sleep(4);
    }
  }
  __syncthreads();
}

__device__ __forceinline__ void block_sum2(float a, float c, float* redA, float* redC,
                                           int tid, float* outA, float* outC) {
  for (int off = 32; off; off >>= 1) {
    a += __shfl_down(a, off);
    c += __shfl_down(c, off);
  }
  if ((tid & 63) == 0) {
    redA[tid >> 6] = a;
    redC[tid >> 6] = c;
  }
  __syncthreads();
  *outA = redA[0] + redA[1] + redA[2] + redA[3];
  *outC = redC[0] + redC[1] + redC[2] + redC[3];
  __syncthreads();
}

// input-attention softmax for step tstep, batch b (fp32 end-to-end)
__device__ __forceinline__ void compute_att(const KParams& p, int b, int tstep, int tid,
                                            float (*hs)[256], float (*qv)[64],
                                            float* att0l, float* att1l) {
  for (int jj = tid; jj < 384; jj += 256) {
    int kb = jj >> 6, c = jj & 63;
    float acc = p.bq[c];
    for (int j = 0; j < 256; ++j) acc += hs[kb][j] * p.wq[j * 64 + c];
    qv[kb][c] = acc;
  }
  __syncthreads();
  if (tid < 64) {
    const float* kxr = p.kx + ((size_t)tstep * 64u + b) * 64u;
    float bkv = p.bk[tid], kxv = kxr[tid];
    for (int kb = 0; kb < 6; ++kb) {
      float q = qv[kb][tid];
      float p0 = q * bkv, p1 = q * kxv;
      for (int off = 32; off; off >>= 1) {
        p0 += __shfl_down(p0, off);
        p1 += __shfl_down(p1, off);
      }
      if (tid == 0) {
        float s0 = p0 * 0.125f, s1 = p1 * 0.125f;  // temperature sqrt(64)=8
        float mx = fmaxf(s0, s1);
        float e0 = expf(s0 - mx), e1 = expf(s1 - mx);
        float inv = 1.f / (e0 + e1);
        att0l[kb] = e0 * inv;
        att1l[kb] = e1 * inv;
      }
    }
  }
  __syncthreads();
}

__global__ __launch_bounds__(256) void rims_seq(KParams p) {
  const int bid = blockIdx.x, tid = threadIdx.x;
  const int wv_ = tid >> 6, lane = tid & 63;
  const int b = bid;  // Phase B identity (bid < 64)

  __shared__ float hs[6][256];
  __shared__ float hx[6][256];
  __shared__ float q2s[6][64], k2s[6][64], v2s[6][64], o2s[6][64];
  __shared__ float qv[6][64];
  __shared__ float scl[4][6][6], a2l[4][6][6];
  __shared__ float att0l[6], att1l[6], maskl[6];
  __shared__ float redA[4], redC[4];

  unsigned nbar = 0;

  // ---- init: load h0, publish packed split-bf16 copy (coherent), att(0) ----
  if (bid < 64) {
    for (int kp = 0; kp < 6; ++kp) {
      float h0 = p.h_in[(size_t)b * 1536u + kp * 256 + tid];
      hs[kp][tid] = h0;
      unsigned short hhi, hlo;
      split2(h0, &hhi, &hlo);
      CSTORE_F(&p.h_pack[(size_t)b * 1536u + kp * 256 + tid], ((unsigned)hhi << 16) | hlo);
    }
    __syncthreads();
    compute_att(p, b, 0, tid, hs, qv, att0l, att1l);
  }
  ++nbar; gbar(p.bar, nbar);

  for (int t = 0; t < T_DIM; ++t) {
    // ======== Phase A: gi_raw = xv[t] @ wi ; gh_raw = h @ wh (split-bf16 MFMA) ========
    if (bid < 72) {
      const int n0 = bid * 64;
      const int row = lane & 15, q8 = (lane >> 4) * 8;
      const size_t aoff = ((size_t)t * 64u + wv_ * 16 + row) * 1024u + q8;
      f32x4 acc[4];
#pragma unroll
      for (int nt = 0; nt < 4; ++nt) acc[nt] = (f32x4){0.f, 0.f, 0.f, 0.f};
      for (int kk = 0; kk < 1024; kk += 32) {
        bf16x8 ah = *(const bf16x8*)(p.xv_hi + aoff + kk);   // plain: L2-hot
        bf16x8 al = *(const bf16x8*)(p.xv_lo + aoff + kk);
#pragma unroll
        for (int nt = 0; nt < 4; ++nt) {
          size_t boff = (size_t)(n0 + nt * 16 + row) * 1024u + kk + q8;
          bf16x8 bh = *(const bf16x8*)(p.wi_hi + boff);      // plain: L2-resident
          bf16x8 bl = *(const bf16x8*)(p.wi_lo + boff);
          acc[nt] = MFMA16(ah, bh, acc[nt]);
          acc[nt] = MFMA16(al, bh, acc[nt]);
          acc[nt] = MFMA16(ah, bl, acc[nt]);
        }
      }
      const int quad = lane >> 4, col = lane & 15;
#pragma unroll
      for (int nt = 0; nt < 4; ++nt)
#pragma unroll
        for (int r = 0; r < 4; ++r) {
          int m = wv_ * 16 + quad * 4 + r;
          CSTORE_F(&p.gi_raw[(size_t)m * NCOL + n0 + nt * 16 + col], acc[nt][r]);
        }
    } else {
      const int j = bid - 72;
      const int gk = j >> 2, q4 = j & 3;
      const int kbb = gk % 6;
      const int nloc0 = q4 * 64;
      const int n0 = (gk / 6) * 1536 + kbb * 256 + nloc0;
      const int row = lane & 15, q8 = (lane >> 4) * 8;
      const unsigned* hp = p.h_pack + (size_t)(wv_ * 16 + row) * 1536u + kbb * 256 + q8;
      const size_t bbase = (size_t)gk * 65536u;
      f32x4 acc[4];
#pragma unroll
      for (int nt = 0; nt < 4; ++nt) acc[nt] = (f32x4){0.f, 0.f, 0.f, 0.f};
#pragma unroll
      for (int half = 0; half < 2; ++half) {
        unsigned u[32];
#pragma unroll
        for (int i = 0; i < 32; ++i)
          u[i] = __hip_atomic_load(hp + half * 128 + (i >> 3) * 32 + (i & 7),
                                   __ATOMIC_RELAXED, __HIP_MEMORY_SCOPE_AGENT);
#pragma unroll
        for (int i = 0; i < 4; ++i) {
          const int kk = half * 128 + i * 32;
          union { unsigned short s[8]; bf16x8 v; } hh, llo;
#pragma unroll
          for (int e = 0; e < 8; ++e) {
            hh.s[e] = (unsigned short)(u[i * 8 + e] >> 16);
            llo.s[e] = (unsigned short)u[i * 8 + e];
          }
#pragma unroll
          for (int nt = 0; nt < 4; ++nt) {
            size_t boff = bbase + (size_t)(nloc0 + nt * 16 + row) * 256u + q8 + kk;
            bf16x8 bh = *(const bf16x8*)(p.wh_hi + boff);    // plain: L2-resident
            bf16x8 bl = *(const bf16x8*)(p.wh_lo + boff);
            acc[nt] = MFMA16(hh.v, bh, acc[nt]);
            acc[nt] = MFMA16(llo.v, bh, acc[nt]);
            acc[nt] = MFMA16(hh.v, bl, acc[nt]);
          }
        }
      }
      const int quad = lane >> 4, col = lane & 15;
#pragma unroll
      for (int nt = 0; nt < 4; ++nt)
#pragma unroll
        for (int r = 0; r < 4; ++r) {
          int m = wv_ * 16 + quad * 4 + r;
          CSTORE_F(&p.gh_raw[(size_t)m * NCOL + n0 + nt * 16 + col], acc[nt][r]);
        }
    }
    ++nbar; gbar(p.bar, nbar);

    // ======== Phase B: one block per b ========
    if (bid < 64) {
      if (tid < 6) {
        float my = att0l[tid];
        int cnt = 0;
        for (int k2 = 0; k2 < 6; ++k2)
          if (att0l[k2] > my || (att0l[k2] == my && k2 < tid)) cnt++;
        maskl[tid] = (cnt < 2) ? 0.f : 1.f;  // 2 largest-null blocks inactive
      }

      // coherent GRU inputs, issued up front (36 independent loads)
      float giv[18], ghv[18];
#pragma unroll
      for (int kp = 0; kp < 6; ++kp)
#pragma unroll
        for (int g = 0; g < 3; ++g) {
          size_t base = (size_t)b * NCOL + g * 1536 + kp * 256 + tid;
          giv[kp * 3 + g] = CLOAD_F(&p.gi_raw[base]);
          ghv[kp * 3 + g] = CLOAD_F(&p.gh_raw[base]);
        }
      __syncthreads();

      // GRU (gate order r,z,n)
      for (int kp = 0; kp < 6; ++kp) {
        float a1 = att1l[kp], a0 = att0l[kp];
        int ci = kp * 256 + tid;
        float gi0 = a1 * giv[kp * 3 + 0] + a0 * p.c0[ci] + p.bi[ci];
        float gi1 = a1 * giv[kp * 3 + 1] + a0 * p.c0[1536 + ci] + p.bi[1536 + ci];
        float gi2 = a1 * giv[kp * 3 + 2] + a0 * p.c0[3072 + ci] + p.bi[3072 + ci];
        float gh0 = ghv[kp * 3 + 0] + p.bh[ci];
        float gh1 = ghv[kp * 3 + 1] + p.bh[1536 + ci];
        float gh2 = ghv[kp * 3 + 2] + p.bh[3072 + ci];
        float r = sigm(gi0 + gh0);
        float z = sigm(gi1 + gh1);
        float n = tanhf(gi2 + r * gh2);
        hx[kp][tid] = (1.f - z) * n + z * hs[kp][tid];
      }
      __syncthreads();

      // q2/k2/v2 for all 6 blocks: 1152 dot-256 jobs
      for (int jj = tid; jj < 1152; jj += 256) {
        int type = jj / 384;
        int r = jj - type * 384;
        int kp = r >> 6, c = r & 63;
        const float* W = (type == 0) ? p.cq : (type == 1) ? p.ck : p.cv;
        float acc = ((type == 0) ? p.cbq : (type == 1) ? p.cbk : p.cbv)[c];
        for (int j = 0; j < 256; ++j) acc += hx[kp][j] * W[j * 64 + c];
        float* dst = (type == 0) ? &q2s[kp][c] : (type == 1) ? &k2s[kp][c] : &v2s[kp][c];
        *dst = acc;
      }
      __syncthreads();

      // scores (temperature sqrt(16)=4)
      if (tid < 144) {
        int hh = tid / 36, rem = tid % 36, qq = rem / 6, kk2 = rem % 6;
        float acc = 0.f;
        for (int d = 0; d < 16; ++d) acc += q2s[qq][hh * 16 + d] * k2s[kk2][hh * 16 + d];
        scl[hh][qq][kk2] = acc * 0.25f;
      }
      __syncthreads();
      if (tid < 24) {
        int hh = tid / 6, qq = tid % 6;
        float mx = -1e30f;
        for (int k2 = 0; k2 < 6; ++k2) mx = fmaxf(mx, scl[hh][qq][k2]);
        float s = 0.f;
        for (int k2 = 0; k2 < 6; ++k2) {
          float e = expf(scl[hh][qq][k2] - mx);
          a2l[hh][qq][k2] = e;
          s += e;
        }
        float inv = 1.f / s;
        for (int k2 = 0; k2 < 6; ++k2) a2l[hh][qq][k2] *= inv;
      }
      __syncthreads();
      for (int jj = tid; jj < 384; jj += 256) {
        int qq = jj >> 6, c = jj & 63, hh = c >> 4;
        float acc = 0.f;
        for (int k2 = 0; k2 < 6; ++k2) acc += a2l[hh][qq][k2] * v2s[k2][c];
        o2s[qq][c] = acc;
      }
      __syncthreads();

      // res = o2 @ cfc + cbfc + hx
      float rr[6];
      for (int kp = 0; kp < 6; ++kp) {
        float acc = p.cbfc[tid] + hx[kp][tid];
        for (int c = 0; c < 64; ++c) acc += o2s[kp][c] * p.cfc[c * 256 + tid];
        rr[kp] = acc;
      }
      __syncthreads();

      // LayerNorm + gated update
      for (int kp = 0; kp < 6; ++kp) {
        float s, sq;
        block_sum2(rr[kp], rr[kp] * rr[kp], redA, redC, tid, &s, &sq);
        float mu = s * (1.f / 256.f);
        float var = sq * (1.f / 256.f) - mu * mu;
        float normed = (rr[kp] - mu) / sqrtf(var + 1e-5f);
        float hxf = hx[kp][tid] + normed * p.ln_g[tid] + p.ln_b[tid];
        float m = maskl[kp];
        float hn = m * hxf + (1.f - m) * hs[kp][tid];
        hs[kp][tid] = hn;
        size_t oidx = ((size_t)t * 64u + b) * 1536u + kp * 256 + tid;
        p.out[oidx] = hn;  // plain: flushed at kernel end
        if (t == T_DIM - 1) p.out[25165824u + (size_t)b * 1536u + kp * 256 + tid] = hn;
        unsigned short hhi, hlo;
        split2(hn, &hhi, &hlo);
        CSTORE_F(&p.h_pack[(size_t)b * 1536u + kp * 256 + tid], ((unsigned)hhi << 16) | hlo);
      }
      __syncthreads();

      if (t < T_DIM - 1) compute_att(p, b, t + 1, tid, hs, qv, att0l, att1l);
    }
    ++nbar; gbar(p.bar, nbar);
  }
}

// ================= host =================

extern "C" void kernel_launch(void* const* d_in, const int* in_sizes, int n_in, void* d_out,
                              int out_size, void* d_ws, size_t ws_size, hipStream_t stream) {
  (void)in_sizes; (void)n_in; (void)out_size; (void)ws_size;
  const float* inp = (const float*)d_in[0];
  const float* h_in = (const float*)d_in[1];
  const float* wq = (const float*)d_in[2];
  const float* bq = (const float*)d_in[3];
  const float* wk = (const float*)d_in[4];
  const float* bk = (const float*)d_in[5];
  const float* wv = (const float*)d_in[6];
  const float* bv = (const float*)d_in[7];
  const float* wi = (const float*)d_in[8];
  const float* wh = (const float*)d_in[9];
  const float* bi = (const float*)d_in[10];
  const float* bh = (const float*)d_in[11];
  const float* cq = (const float*)d_in[12];
  const float* cbq = (const float*)d_in[13];
  const float* ck = (const float*)d_in[14];
  const float* cbk = (const float*)d_in[15];
  const float* cv = (const float*)d_in[16];
  const float* cbv = (const float*)d_in[17];
  const float* cfc = (const float*)d_in[18];
  const float* cbfc = (const float*)d_in[19];
  const float* ln_g = (const float*)d_in[20];
  const float* ln_b = (const float*)d_in[21];

  char* ws = (char*)d_ws;
  const size_t o_wv_hi = 0;           // 3,145,728
  const size_t o_wv_lo = 3145728;     // 3,145,728
  const size_t o_wi_hi = 6291456;     // 9,437,184
  const size_t o_wi_lo = 15728640;    // 9,437,184
  const size_t o_wh_hi = 25165824;    // 2,359,296
  const size_t o_wh_lo = 27525120;    // 2,359,296
  const size_t o_xv_hi = 29884416;    // 33,554,432
  const size_t o_xv_lo = 63438848;    // 33,554,432
  const size_t o_kx = 96993280;       // 4,194,304
  const size_t o_c0 = 101187584;      // 18,432
  const size_t o_gi = 101206016;      // 1,179,648
  const size_t o_gh = 102385664;      // 1,179,648
  const size_t o_hpack = 103565312;   // 393,216
  const size_t o_bar = 103958528;     // 1,024 (8 counters x 128 B)

  unsigned short* wv_hi = (unsigned short*)(ws + o_wv_hi);
  unsigned short* wv_lo = (unsigned short*)(ws + o_wv_lo);
  unsigned short* wi_hi = (unsigned short*)(ws + o_wi_hi);
  unsigned short* wi_lo = (unsigned short*)(ws + o_wi_lo);
  unsigned short* wh_hi = (unsigned short*)(ws + o_wh_hi);
  unsigned short* wh_lo = (unsigned short*)(ws + o_wh_lo);
  unsigned short* xv_hi = (unsigned short*)(ws + o_xv_hi);
  unsigned short* xv_lo = (unsigned short*)(ws + o_xv_lo);
  float* kx = (float*)(ws + o_kx);
  float* c0 = (float*)(ws + o_c0);

  hipMemsetAsync(ws + o_bar, 0, 1024, stream);
  convert_weights<<<2048, 256, 0, stream>>>(wv, wi, wh, wv_hi, wv_lo, wi_hi, wi_lo, wh_hi, wh_lo);
  kx_kernel<<<1024, 256, 0, stream>>>(inp, wk, bk, kx);
  xv_gemm<<<dim3(8, 128), 256, 0, stream>>>(inp, wv_hi, wv_lo, bv, xv_hi, xv_lo);
  c0_kernel<<<18, 256, 0, stream>>>(bv, wi, c0);

  KParams prm;
  prm.h_in = h_in; prm.wq = wq; prm.bq = bq; prm.bk = bk;
  prm.bi = bi; prm.bh = bh;
  prm.cq = cq; prm.cbq = cbq; prm.ck = ck; prm.cbk = cbk;
  prm.cv = cv; prm.cbv = cbv; prm.cfc = cfc; prm.cbfc = cbfc;
  prm.ln_g = ln_g; prm.ln_b = ln_b;
  prm.xv_hi = xv_hi; prm.xv_lo = xv_lo;
  prm.wi_hi = wi_hi; prm.wi_lo = wi_lo;
  prm.wh_hi = wh_hi; prm.wh_lo = wh_lo;
  prm.kx = kx; prm.c0 = c0;
  prm.gi_raw = (float*)(ws + o_gi);
  prm.gh_raw = (float*)(ws + o_gh);
  prm.h_pack = (unsigned*)(ws + o_hpack);
  prm.bar = (unsigned*)(ws + o_bar);
  prm.out = (float*)d_out;

  rims_seq<<<GRID_N, 256, 0, stream>>>(prm);
}